// Round 6
// baseline (1859.017 us; speedup 1.0000x reference)
//
#include <hip/hip_runtime.h>
#include <stdint.h>

#define HW    16384
#define NB    64
#define WPER  28970
#define NBIAS 156
#define EPSB  1e-5f
#define PROW  132            // padded row stride (floats): 1 left + 128 + 3 right
#define PLSZ  (130*132)      // padded plane: 130 rows x 132 cols = 17160 floats

typedef float f4 __attribute__((ext_vector_type(4)));
typedef f4 uf4 __attribute__((aligned(4)));   // 4-byte-aligned float4 loads

// ---- prep: gather per-sample weights -> fp32 ws, fold BN scale into weights.
__global__ void prep_w(const float* __restrict__ w1, const float* __restrict__ w2,
                       const float* __restrict__ w3, const float* __restrict__ w4,
                       const float* __restrict__ g,  const float* __restrict__ be,
                       const float* __restrict__ mu, const float* __restrict__ va,
                       float* __restrict__ wout, float* __restrict__ bias)
{
    const int start[11] = {0,1080,2376,3672,8424,13608,16200,20952,26136,28728,28970};
    const int cink[10]  = {90,108,108,198,216,216,198,216,216,22};
    const int bnoff[10] = {0,12,24,36,60,84,96,120,144,0};
    long tid = (long)blockIdx.x * 256 + threadIdx.x;
    long total = (long)NB * WPER, stride = (long)gridDim.x * 256;
    for (long i = tid; i < total; i += stride) {
        int b = (int)(i / WPER), p = (int)(i - (long)b * WPER);
        const float* src; long si;
        if      (p <  3672) { src = w1; si = (long)b *  3672 +  p;          }
        else if (p < 16200) { src = w2; si = (long)b * 12528 + (p -  3672); }
        else if (p < 28728) { src = w3; si = (long)b * 12528 + (p - 16200); }
        else                { src = w4; si = (long)b *   242 + (p - 28728); }
        float w = src[si];
        int l = 0;
        while (p >= start[l + 1]) ++l;
        if (l < 9) {
            int o  = (p - start[l]) / cink[l];
            int bi = bnoff[l] + o;
            w *= g[bi] * rsqrtf(va[bi] + EPSB);
        }
        wout[i] = w;
    }
    if (tid < NBIAS) {
        float s = g[tid] * rsqrtf(va[tid] + EPSB);
        bias[tid] = be[tid] - mu[tid] * s;
    }
}

// ---- copy x (64x10 planes, 128x128) into zero-padded 130x132 planes.
__global__ void pad_x(const float* __restrict__ x, float* __restrict__ padx)
{
    int plane = blockIdx.x;                       // b*10 + ch, 640 planes
    const float* __restrict__ src = x + (long)plane * HW;
    float* __restrict__ dst = padx + (long)plane * PLSZ;
    for (int i = threadIdx.x; i < PLSZ; i += 256) {
        int r = i / PROW, c = i - r * PROW;
        float v = 0.f;
        if (r >= 1 && r <= 128 && c >= 1 && c <= 128)
            v = src[(r - 1) * 128 + (c - 1)];
        dst[i] = v;
    }
}

// ---- zero the borders of padded planes (interiors are overwritten).
__global__ void zero_borders(float* __restrict__ base)
{
    float* __restrict__ p = base + (long)blockIdx.x * PLSZ;
    for (int j = threadIdx.x; j < 776; j += 256) {
        int idx;
        if      (j < 132) idx = j;                              // row 0
        else if (j < 264) idx = 129 * PROW + (j - 132);         // row 129
        else { int k = j - 264; int r = 1 + (k >> 2); int c4 = k & 3;
               idx = r * PROW + (c4 == 0 ? 0 : 128 + c4); }     // cols 0,129,130,131
        p[idx] = 0.f;
    }
}

// ---- per-sample 3x3 conv (+folded BN, ReLU), padded in/out planes.
// Thread: 2 horizontal px. Channel loops FULLY unrolled so the scheduler
// hoists tap loads many channels ahead (software pipelining within the
// 128-VGPR budget from __launch_bounds__(256,4)).
template<int CA, int CX, int CO>
__global__ __launch_bounds__(256, 4)
void conv3(const float* __restrict__ actIn, const float* __restrict__ padx,
           const float* __restrict__ wAll, int wOff,
           const float* __restrict__ bias, int bnOff,
           float* __restrict__ actOut, int b0)
{
    constexpr int CIN = CA + CX;
    const int s  = blockIdx.y, gb = b0 + s;
    const int t  = threadIdx.x;
    const int xc = t & 63;                      // 64 threads x 2 px = 128 cols
    const int y  = blockIdx.x * 4 + (t >> 6);   // interior row 0..127
    const int tap0 = y * PROW + 2 * xc;         // padded row y, padded col 2xc

    const float* __restrict__ wb = wAll + (long)gb * WPER + wOff;

    float acc[2 * CO];
#pragma unroll
    for (int o = 0; o < CO; ++o) {
        float b_ = bias[bnOff + o];
        acc[2 * o] = b_; acc[2 * o + 1] = b_;
    }

#pragma unroll
    for (int c = 0; c < CA; ++c) {
        const float* __restrict__ ip = actIn + ((long)s * CA + c) * PLSZ + tap0;
        f4 t0 = *(const uf4*)(ip);
        f4 t1 = *(const uf4*)(ip + PROW);
        f4 t2 = *(const uf4*)(ip + 2 * PROW);
        float tp[12] = {t0.x,t0.y,t0.z,t0.w, t1.x,t1.y,t1.z,t1.w, t2.x,t2.y,t2.z,t2.w};
        const float* __restrict__ wc = wb + c * 9;
#pragma unroll
        for (int o = 0; o < CO; ++o) {
            const float* __restrict__ w9 = wc + o * CIN * 9;
#pragma unroll
            for (int kr = 0; kr < 3; ++kr)
#pragma unroll
                for (int kc = 0; kc < 3; ++kc) {
                    float w = w9[kr * 3 + kc];
                    acc[2 * o]     = fmaf(w, tp[kr * 4 + kc],     acc[2 * o]);
                    acc[2 * o + 1] = fmaf(w, tp[kr * 4 + kc + 1], acc[2 * o + 1]);
                }
        }
    }
#pragma unroll
    for (int c = 0; c < CX; ++c) {
        const float* __restrict__ ip = padx + ((long)gb * 10 + c) * PLSZ + tap0;
        f4 t0 = *(const uf4*)(ip);
        f4 t1 = *(const uf4*)(ip + PROW);
        f4 t2 = *(const uf4*)(ip + 2 * PROW);
        float tp[12] = {t0.x,t0.y,t0.z,t0.w, t1.x,t1.y,t1.z,t1.w, t2.x,t2.y,t2.z,t2.w};
        const float* __restrict__ wc = wb + (CA + c) * 9;
#pragma unroll
        for (int o = 0; o < CO; ++o) {
            const float* __restrict__ w9 = wc + o * CIN * 9;
#pragma unroll
            for (int kr = 0; kr < 3; ++kr)
#pragma unroll
                for (int kc = 0; kc < 3; ++kc) {
                    float w = w9[kr * 3 + kc];
                    acc[2 * o]     = fmaf(w, tp[kr * 4 + kc],     acc[2 * o]);
                    acc[2 * o + 1] = fmaf(w, tp[kr * 4 + kc + 1], acc[2 * o + 1]);
                }
        }
    }

    long obase = (long)s * CO * PLSZ + (y + 1) * PROW + 2 * xc + 1;
#pragma unroll
    for (int o = 0; o < CO; ++o) {
        actOut[obase + (long)o * PLSZ]     = fmaxf(acc[2 * o], 0.f);
        actOut[obase + (long)o * PLSZ + 1] = fmaxf(acc[2 * o + 1], 0.f);
    }
}

// ---- final per-sample 1x1 conv, padded inputs, unpadded fp32 output.
template<int CA, int CX, int CO>
__global__ __launch_bounds__(256, 4)
void conv1x1(const float* __restrict__ actIn, const float* __restrict__ padx,
             const float* __restrict__ wAll, int wOff,
             float* __restrict__ outF, int b0)
{
    constexpr int CIN = CA + CX;
    const int s = blockIdx.y, gb = b0 + s;
    const int p = blockIdx.x * 256 + threadIdx.x;
    const int off = ((p >> 7) + 1) * PROW + (p & 127) + 1;
    const float* __restrict__ wb = wAll + (long)gb * WPER + wOff;

    float acc[CO];
#pragma unroll
    for (int o = 0; o < CO; ++o) acc[o] = 0.f;

#pragma unroll
    for (int c = 0; c < CA; ++c) {
        float v = actIn[((long)s * CA + c) * PLSZ + off];
#pragma unroll
        for (int o = 0; o < CO; ++o) acc[o] = fmaf(wb[o * CIN + c], v, acc[o]);
    }
#pragma unroll
    for (int c = 0; c < CX; ++c) {
        float v = padx[((long)gb * 10 + c) * PLSZ + off];
#pragma unroll
        for (int o = 0; o < CO; ++o) acc[o] = fmaf(wb[o * CIN + CA + c], v, acc[o]);
    }
#pragma unroll
    for (int o = 0; o < CO; ++o)
        outF[((long)gb * CO + o) * HW + p] = acc[o];
}

extern "C" void kernel_launch(void* const* d_in, const int* in_sizes, int n_in,
                              void* d_out, int out_size, void* d_ws, size_t ws_size,
                              hipStream_t stream)
{
    const float *x = (const float*)d_in[0], *w1 = (const float*)d_in[1],
                *w2 = (const float*)d_in[2], *w3 = (const float*)d_in[3],
                *w4 = (const float*)d_in[4], *g  = (const float*)d_in[5],
                *be = (const float*)d_in[6], *mu = (const float*)d_in[7],
                *va = (const float*)d_in[8];
    if (n_in == 9) {   // identify by size signature (fallback: dict order)
        const float* big801[2] = {nullptr, nullptr}; int n801 = 0;
        const float* bn156[4]  = {nullptr, nullptr, nullptr, nullptr}; int n156 = 0;
        const float *fx = nullptr, *fw1 = nullptr, *fw4 = nullptr;
        for (int i = 0; i < 9; ++i) {
            int sz = in_sizes[i];
            if      (sz == 10485760) fx  = (const float*)d_in[i];
            else if (sz ==   235008) fw1 = (const float*)d_in[i];
            else if (sz ==   801792) { if (n801 < 2) big801[n801++] = (const float*)d_in[i]; }
            else if (sz ==    15488) fw4 = (const float*)d_in[i];
            else if (sz ==      156) { if (n156 < 4) bn156[n156++] = (const float*)d_in[i]; }
        }
        if (fx && fw1 && fw4 && n801 == 2 && n156 == 4) {
            x = fx; w1 = fw1; w2 = big801[0]; w3 = big801[1]; w4 = fw4;
            g = bn156[0]; be = bn156[1]; mu = bn156[2]; va = bn156[3];
        }
    }
    float* out = (float*)d_out;

    // ws layout: [weights 7.42MB][bias 1KB][padx 43.9MB][bufA|bufB (padded)]
    const size_t wgtB  = (size_t)NB * WPER * 4;
    const size_t biasB = 1024;
    const size_t padxB = (size_t)NB * 10 * PLSZ * 4;
    const size_t hdr   = wgtB + biasB + padxB;
    const size_t per2  = 2ull * 24 * PLSZ * 4;      // ping+pong per sample
    float* wcvt  = (float*)d_ws;
    float* bias  = (float*)((char*)d_ws + wgtB);
    float* padx  = (float*)((char*)d_ws + wgtB + biasB);
    size_t avail = ws_size > hdr ? ws_size - hdr : per2;
    int chunk = (int)(avail / per2);
    if (chunk > NB) chunk = NB;
    if (chunk < 1)  chunk = 1;
    float* bufA = (float*)((char*)d_ws + hdr);
    float* bufB = bufA + (size_t)chunk * 24 * PLSZ;

    prep_w<<<2048, 256, 0, stream>>>(w1, w2, w3, w4, g, be, mu, va, wcvt, bias);
    pad_x<<<NB * 10, 256, 0, stream>>>(x, padx);
    zero_borders<<<chunk * 48, 256, 0, stream>>>(bufA);   // bufA+bufB contiguous

    for (int b0 = 0; b0 < NB; b0 += chunk) {
        int nb = (NB - b0 < chunk) ? (NB - b0) : chunk;
        dim3 g3(32, nb);    // 32 row-tiles x 4 rows
        dim3 g1(64, nb);
        conv3< 0,10,12><<<g3,256,0,stream>>>(bufA,  padx, wcvt,     0, bias,   0, bufA, b0);
        conv3<12, 0,12><<<g3,256,0,stream>>>(bufA,  padx, wcvt,  1080, bias,  12, bufB, b0);
        conv3<12, 0,12><<<g3,256,0,stream>>>(bufB,  padx, wcvt,  2376, bias,  24, bufA, b0);
        conv3<12,10,24><<<g3,256,0,stream>>>(bufA,  padx, wcvt,  3672, bias,  36, bufB, b0);
        conv3<24, 0,24><<<g3,256,0,stream>>>(bufB,  padx, wcvt,  8424, bias,  60, bufA, b0);
        conv3<24, 0,12><<<g3,256,0,stream>>>(bufA,  padx, wcvt, 13608, bias,  84, bufB, b0);
        conv3<12,10,24><<<g3,256,0,stream>>>(bufB,  padx, wcvt, 16200, bias,  96, bufA, b0);
        conv3<24, 0,24><<<g3,256,0,stream>>>(bufA,  padx, wcvt, 20952, bias, 120, bufB, b0);
        conv3<24, 0,12><<<g3,256,0,stream>>>(bufB,  padx, wcvt, 26136, bias, 144, bufA, b0);
        conv1x1<12,10,11><<<g1,256,0,stream>>>(bufA, padx, wcvt, 28728, out, b0);
    }
}

// Round 7
// 966.193 us; speedup vs baseline: 1.9241x; 1.9241x over previous
//
#include <hip/hip_runtime.h>
#include <stdint.h>

#define HW    16384
#define NB    64
#define WPER  28970
#define NBIAS 156
#define EPSB  1e-5f
#define PROW  132            // padded row stride (floats): 1 left + 128 + 3 right
#define PLSZ  (130*132)      // padded plane: 130 rows x 132 cols = 17160 floats

typedef float f4 __attribute__((ext_vector_type(4)));
typedef f4 uf4 __attribute__((aligned(4)));   // 4-byte-aligned float4 loads

// ---- prep: gather per-sample weights -> fp32 ws, fold BN scale into weights.
__global__ void prep_w(const float* __restrict__ w1, const float* __restrict__ w2,
                       const float* __restrict__ w3, const float* __restrict__ w4,
                       const float* __restrict__ g,  const float* __restrict__ be,
                       const float* __restrict__ mu, const float* __restrict__ va,
                       float* __restrict__ wout, float* __restrict__ bias)
{
    const int start[11] = {0,1080,2376,3672,8424,13608,16200,20952,26136,28728,28970};
    const int cink[10]  = {90,108,108,198,216,216,198,216,216,22};
    const int bnoff[10] = {0,12,24,36,60,84,96,120,144,0};
    long tid = (long)blockIdx.x * 256 + threadIdx.x;
    long total = (long)NB * WPER, stride = (long)gridDim.x * 256;
    for (long i = tid; i < total; i += stride) {
        int b = (int)(i / WPER), p = (int)(i - (long)b * WPER);
        const float* src; long si;
        if      (p <  3672) { src = w1; si = (long)b *  3672 +  p;          }
        else if (p < 16200) { src = w2; si = (long)b * 12528 + (p -  3672); }
        else if (p < 28728) { src = w3; si = (long)b * 12528 + (p - 16200); }
        else                { src = w4; si = (long)b *   242 + (p - 28728); }
        float w = src[si];
        int l = 0;
        while (p >= start[l + 1]) ++l;
        if (l < 9) {
            int o  = (p - start[l]) / cink[l];
            int bi = bnoff[l] + o;
            w *= g[bi] * rsqrtf(va[bi] + EPSB);
        }
        wout[i] = w;
    }
    if (tid < NBIAS) {
        float s = g[tid] * rsqrtf(va[tid] + EPSB);
        bias[tid] = be[tid] - mu[tid] * s;
    }
}

// ---- copy x (64x10 planes, 128x128) into zero-padded 130x132 planes.
__global__ void pad_x(const float* __restrict__ x, float* __restrict__ padx)
{
    int plane = blockIdx.x;                       // b*10 + ch, 640 planes
    const float* __restrict__ src = x + (long)plane * HW;
    float* __restrict__ dst = padx + (long)plane * PLSZ;
    for (int i = threadIdx.x; i < PLSZ; i += 256) {
        int r = i / PROW, c = i - r * PROW;
        float v = 0.f;
        if (r >= 1 && r <= 128 && c >= 1 && c <= 128)
            v = src[(r - 1) * 128 + (c - 1)];
        dst[i] = v;
    }
}

// ---- zero the borders of padded planes (interiors are overwritten).
__global__ void zero_borders(float* __restrict__ base)
{
    float* __restrict__ p = base + (long)blockIdx.x * PLSZ;
    for (int j = threadIdx.x; j < 776; j += 256) {
        int idx;
        if      (j < 132) idx = j;                              // row 0
        else if (j < 264) idx = 129 * PROW + (j - 132);         // row 129
        else { int k = j - 264; int r = 1 + (k >> 2); int c4 = k & 3;
               idx = r * PROW + (c4 == 0 ? 0 : 128 + c4); }     // cols 0,129,130,131
        p[idx] = 0.f;
    }
}

// ---- per-sample 3x3 conv (+folded BN, ReLU), padded in/out planes.
// Thread: 2 horizontal px. `#pragma unroll 1` c-loop (round-6 full unroll
// spilled: VGPR capped 40 + WRITE_SIZE +44MB scratch). Depth-2 rotating
// prefetch: consume taps loaded last iteration, issue next iteration's
// loads before the 432-FMA body -> loads get ~864 cyc in flight.
template<int CA, int CX, int CO>
__global__ __launch_bounds__(256, 4)
void conv3(const float* __restrict__ actIn, const float* __restrict__ padx,
           const float* __restrict__ wAll, int wOff,
           const float* __restrict__ bias, int bnOff,
           float* __restrict__ actOut, int b0)
{
    constexpr int CIN = CA + CX;
    const int s  = blockIdx.y, gb = b0 + s;
    const int t  = threadIdx.x;
    const int xc = t & 63;                      // 64 threads x 2 px = 128 cols
    const int y  = blockIdx.x * 4 + (t >> 6);   // interior row 0..127
    const int tap0 = y * PROW + 2 * xc;         // padded row y, padded col 2xc

    const float* __restrict__ wb = wAll + (long)gb * WPER + wOff;
    const float* __restrict__ baseA = actIn + (long)s * CA * PLSZ + tap0;
    const float* __restrict__ baseX = padx + (long)gb * 10 * PLSZ + tap0;

    // pointer for virtual channel u in [0, CIN): first CA from actIn, rest x
    auto chp = [&](int u) -> const float* {
        if constexpr (CA == 0) return baseX + (long)u * PLSZ;
        else if constexpr (CX == 0) return baseA + (long)u * PLSZ;
        else return (u < CA) ? baseA + (long)u * PLSZ
                             : baseX + (long)(u - CA) * PLSZ;
    };

    float acc[2 * CO];
#pragma unroll
    for (int o = 0; o < CO; ++o) {
        float b_ = bias[bnOff + o];
        acc[2 * o] = b_; acc[2 * o + 1] = b_;
    }

    // prologue: issue loads for channel 0
    const float* ip0 = chp(0);
    f4 n0 = *(const uf4*)(ip0);
    f4 n1 = *(const uf4*)(ip0 + PROW);
    f4 n2 = *(const uf4*)(ip0 + 2 * PROW);

#pragma unroll 1
    for (int c = 0; c < CIN; ++c) {
        f4 t0 = n0, t1 = n1, t2 = n2;
        int cn = (c + 1 < CIN) ? c + 1 : CIN - 1;   // clamped, branchless
        const float* np = chp(cn);
        n0 = *(const uf4*)(np);
        n1 = *(const uf4*)(np + PROW);
        n2 = *(const uf4*)(np + 2 * PROW);

        float tp[12] = {t0.x,t0.y,t0.z,t0.w, t1.x,t1.y,t1.z,t1.w, t2.x,t2.y,t2.z,t2.w};
        const float* __restrict__ wc = wb + c * 9;
#pragma unroll
        for (int o = 0; o < CO; ++o) {
            const float* __restrict__ w9 = wc + o * CIN * 9;
#pragma unroll
            for (int kr = 0; kr < 3; ++kr)
#pragma unroll
                for (int kc = 0; kc < 3; ++kc) {
                    float w = w9[kr * 3 + kc];
                    acc[2 * o]     = fmaf(w, tp[kr * 4 + kc],     acc[2 * o]);
                    acc[2 * o + 1] = fmaf(w, tp[kr * 4 + kc + 1], acc[2 * o + 1]);
                }
        }
    }

    long obase = (long)s * CO * PLSZ + (y + 1) * PROW + 2 * xc + 1;
#pragma unroll
    for (int o = 0; o < CO; ++o) {
        actOut[obase + (long)o * PLSZ]     = fmaxf(acc[2 * o], 0.f);
        actOut[obase + (long)o * PLSZ + 1] = fmaxf(acc[2 * o + 1], 0.f);
    }
}

// ---- final per-sample 1x1 conv, padded inputs, unpadded fp32 output.
template<int CA, int CX, int CO>
__global__ __launch_bounds__(256, 4)
void conv1x1(const float* __restrict__ actIn, const float* __restrict__ padx,
             const float* __restrict__ wAll, int wOff,
             float* __restrict__ outF, int b0)
{
    constexpr int CIN = CA + CX;
    const int s = blockIdx.y, gb = b0 + s;
    const int p = blockIdx.x * 256 + threadIdx.x;
    const int off = ((p >> 7) + 1) * PROW + (p & 127) + 1;
    const float* __restrict__ wb = wAll + (long)gb * WPER + wOff;
    const float* __restrict__ baseA = actIn + (long)s * CA * PLSZ + off;
    const float* __restrict__ baseX = padx + (long)gb * 10 * PLSZ + off;

    auto chp = [&](int u) -> const float* {
        return (u < CA) ? baseA + (long)u * PLSZ
                        : baseX + (long)(u - CA) * PLSZ;
    };

    float acc[CO];
#pragma unroll
    for (int o = 0; o < CO; ++o) acc[o] = 0.f;

    float nv = *chp(0);
#pragma unroll 1
    for (int c = 0; c < CIN; ++c) {
        float v = nv;
        int cn = (c + 1 < CIN) ? c + 1 : CIN - 1;
        nv = *chp(cn);
#pragma unroll
        for (int o = 0; o < CO; ++o) acc[o] = fmaf(wb[o * CIN + c], v, acc[o]);
    }
#pragma unroll
    for (int o = 0; o < CO; ++o)
        outF[((long)gb * CO + o) * HW + p] = acc[o];
}

extern "C" void kernel_launch(void* const* d_in, const int* in_sizes, int n_in,
                              void* d_out, int out_size, void* d_ws, size_t ws_size,
                              hipStream_t stream)
{
    const float *x = (const float*)d_in[0], *w1 = (const float*)d_in[1],
                *w2 = (const float*)d_in[2], *w3 = (const float*)d_in[3],
                *w4 = (const float*)d_in[4], *g  = (const float*)d_in[5],
                *be = (const float*)d_in[6], *mu = (const float*)d_in[7],
                *va = (const float*)d_in[8];
    if (n_in == 9) {   // identify by size signature (fallback: dict order)
        const float* big801[2] = {nullptr, nullptr}; int n801 = 0;
        const float* bn156[4]  = {nullptr, nullptr, nullptr, nullptr}; int n156 = 0;
        const float *fx = nullptr, *fw1 = nullptr, *fw4 = nullptr;
        for (int i = 0; i < 9; ++i) {
            int sz = in_sizes[i];
            if      (sz == 10485760) fx  = (const float*)d_in[i];
            else if (sz ==   235008) fw1 = (const float*)d_in[i];
            else if (sz ==   801792) { if (n801 < 2) big801[n801++] = (const float*)d_in[i]; }
            else if (sz ==    15488) fw4 = (const float*)d_in[i];
            else if (sz ==      156) { if (n156 < 4) bn156[n156++] = (const float*)d_in[i]; }
        }
        if (fx && fw1 && fw4 && n801 == 2 && n156 == 4) {
            x = fx; w1 = fw1; w2 = big801[0]; w3 = big801[1]; w4 = fw4;
            g = bn156[0]; be = bn156[1]; mu = bn156[2]; va = bn156[3];
        }
    }
    float* out = (float*)d_out;

    // ws layout: [weights 7.42MB][bias 1KB][padx 43.9MB][bufA|bufB (padded)]
    const size_t wgtB  = (size_t)NB * WPER * 4;
    const size_t biasB = 1024;
    const size_t padxB = (size_t)NB * 10 * PLSZ * 4;
    const size_t hdr   = wgtB + biasB + padxB;
    const size_t per2  = 2ull * 24 * PLSZ * 4;      // ping+pong per sample
    float* wcvt  = (float*)d_ws;
    float* bias  = (float*)((char*)d_ws + wgtB);
    float* padx  = (float*)((char*)d_ws + wgtB + biasB);
    size_t avail = ws_size > hdr ? ws_size - hdr : per2;
    int chunk = (int)(avail / per2);
    if (chunk > NB) chunk = NB;
    if (chunk < 1)  chunk = 1;
    float* bufA = (float*)((char*)d_ws + hdr);
    float* bufB = bufA + (size_t)chunk * 24 * PLSZ;

    prep_w<<<2048, 256, 0, stream>>>(w1, w2, w3, w4, g, be, mu, va, wcvt, bias);
    pad_x<<<NB * 10, 256, 0, stream>>>(x, padx);
    zero_borders<<<chunk * 48, 256, 0, stream>>>(bufA);   // bufA+bufB contiguous

    for (int b0 = 0; b0 < NB; b0 += chunk) {
        int nb = (NB - b0 < chunk) ? (NB - b0) : chunk;
        dim3 g3(32, nb);    // 32 row-tiles x 4 rows
        dim3 g1(64, nb);
        conv3< 0,10,12><<<g3,256,0,stream>>>(bufA,  padx, wcvt,     0, bias,   0, bufA, b0);
        conv3<12, 0,12><<<g3,256,0,stream>>>(bufA,  padx, wcvt,  1080, bias,  12, bufB, b0);
        conv3<12, 0,12><<<g3,256,0,stream>>>(bufB,  padx, wcvt,  2376, bias,  24, bufA, b0);
        conv3<12,10,24><<<g3,256,0,stream>>>(bufA,  padx, wcvt,  3672, bias,  36, bufB, b0);
        conv3<24, 0,24><<<g3,256,0,stream>>>(bufB,  padx, wcvt,  8424, bias,  60, bufA, b0);
        conv3<24, 0,12><<<g3,256,0,stream>>>(bufA,  padx, wcvt, 13608, bias,  84, bufB, b0);
        conv3<12,10,24><<<g3,256,0,stream>>>(bufB,  padx, wcvt, 16200, bias,  96, bufA, b0);
        conv3<24, 0,24><<<g3,256,0,stream>>>(bufA,  padx, wcvt, 20952, bias, 120, bufB, b0);
        conv3<24, 0,12><<<g3,256,0,stream>>>(bufB,  padx, wcvt, 26136, bias, 144, bufA, b0);
        conv1x1<12,10,11><<<g1,256,0,stream>>>(bufA, padx, wcvt, 28728, out, b0);
    }
}

// Round 8
// 792.349 us; speedup vs baseline: 2.3462x; 1.2194x over previous
//
#include <hip/hip_runtime.h>
#include <stdint.h>

#define HW    16384
#define NB    64
#define WPER  28970
#define NBIAS 156
#define EPSB  1e-5f
#define PROW  132            // padded row stride (floats)
#define PLSZ  (130*132)      // padded plane floats

typedef float f4 __attribute__((ext_vector_type(4)));
typedef float f2 __attribute__((ext_vector_type(2)));
typedef f4 uf4 __attribute__((aligned(4)));
typedef f2 uf2 __attribute__((aligned(4)));

// ---- prep: gather per-sample weights -> fp32 ws, fold BN scale, and
// REORDER each layer to [c][o][k] so one c-iteration's weights for a
// 12-wide o-block are 108 contiguous floats (s_load_dwordx16 chains).
__global__ void prep_w(const float* __restrict__ w1, const float* __restrict__ w2,
                       const float* __restrict__ w3, const float* __restrict__ w4,
                       const float* __restrict__ g,  const float* __restrict__ be,
                       const float* __restrict__ mu, const float* __restrict__ va,
                       float* __restrict__ wout, float* __restrict__ bias)
{
    const int start[10] = {0,1080,2376,3672,8424,13608,16200,20952,26136,28728};
    const int COt[10]   = {12,12,12,24,24,12,24,24,12,11};
    const int CIt[10]   = {10,12,12,22,24,24,22,24,24,22};
    const int bnoff[10] = {0,12,24,36,60,84,96,120,144,0};
    long tid = (long)blockIdx.x * 256 + threadIdx.x;
    long total = (long)NB * WPER, stride = (long)gridDim.x * 256;
    for (long idx = tid; idx < total; idx += stride) {
        int b = (int)(idx / WPER), p = (int)(idx - (long)b * WPER);
        int l = 9;
        while (p < start[l]) --l;                 // layer of dest index
        int i = p - start[l];
        int CO = COt[l], CI = CIt[l];
        int srcp, o;
        if (l < 9) {                              // dest [c][o][k] <- src [o][c][k]
            int c  = i / (CO * 9);
            int r  = i - c * CO * 9;
            o      = r / 9;
            int k  = r - o * 9;
            srcp   = start[l] + (o * CI + c) * 9 + k;
        } else {                                  // 1x1: dest [c][o] <- src [o][c]
            int c  = i / CO;
            o      = i - c * CO;
            srcp   = start[l] + o * CI + c;
        }
        const float* src; long si;
        if      (srcp <  3672) { src = w1; si = (long)b *  3672 +  srcp;          }
        else if (srcp < 16200) { src = w2; si = (long)b * 12528 + (srcp -  3672); }
        else if (srcp < 28728) { src = w3; si = (long)b * 12528 + (srcp - 16200); }
        else                   { src = w4; si = (long)b *   242 + (srcp - 28728); }
        float w = src[si];
        if (l < 9) {
            int bi = bnoff[l] + o;
            w *= g[bi] * rsqrtf(va[bi] + EPSB);
        }
        wout[idx] = w;
    }
    if (tid < NBIAS) {
        float s = g[tid] * rsqrtf(va[tid] + EPSB);
        bias[tid] = be[tid] - mu[tid] * s;
    }
}

// ---- copy x into zero-padded 130x132 planes.
__global__ void pad_x(const float* __restrict__ x, float* __restrict__ padx)
{
    int plane = blockIdx.x;
    const float* __restrict__ src = x + (long)plane * HW;
    float* __restrict__ dst = padx + (long)plane * PLSZ;
    for (int i = threadIdx.x; i < PLSZ; i += 256) {
        int r = i / PROW, c = i - r * PROW;
        float v = 0.f;
        if (r >= 1 && r <= 128 && c >= 1 && c <= 128)
            v = src[(r - 1) * 128 + (c - 1)];
        dst[i] = v;
    }
}

// ---- zero borders of padded planes.
__global__ void zero_borders(float* __restrict__ base)
{
    float* __restrict__ p = base + (long)blockIdx.x * PLSZ;
    for (int j = threadIdx.x; j < 776; j += 256) {
        int idx;
        if      (j < 132) idx = j;
        else if (j < 264) idx = 129 * PROW + (j - 132);
        else { int k = j - 264; int r = 1 + (k >> 2); int c4 = k & 3;
               idx = r * PROW + (c4 == 0 ? 0 : 128 + c4); }
        p[idx] = 0.f;
    }
}

// ---- per-sample 3x3 conv (+folded BN, ReLU). 4 px/thread, COBLK=12
// outputs/block (z-split for CO=24). Per c-iter: 18 tap floats + 108
// contiguous weight scalars -> 432 FMAs.
template<int CA, int CX, int COTOT, int COBLK>
__global__ __launch_bounds__(256, 4)
void conv3(const float* __restrict__ actIn, const float* __restrict__ padx,
           const float* __restrict__ wAll, int wOff,
           const float* __restrict__ bias, int bnOff,
           float* __restrict__ actOut, int b0)
{
    constexpr int CIN = CA + CX;
    const int s  = blockIdx.y, gb = b0 + s;
    const int o0 = blockIdx.z * COBLK;
    const int t  = threadIdx.x;
    const int xc = t & 31;                      // 32 col-groups x 4 px
    const int y  = blockIdx.x * 8 + (t >> 5);   // interior row 0..127
    const int tap0 = y * PROW + 4 * xc;         // top-left of 3x6 tap window

    const float* __restrict__ wb = wAll + (long)gb * WPER + wOff;  // [c][COTOT][9]
    const float* __restrict__ baseA = actIn + (long)s * CA * PLSZ + tap0;
    const float* __restrict__ baseX = padx + (long)gb * 10 * PLSZ + tap0;

    auto chp = [&](int u) -> const float* {
        if constexpr (CA == 0) return baseX + (long)u * PLSZ;
        else if constexpr (CX == 0) return baseA + (long)u * PLSZ;
        else return (u < CA) ? baseA + (long)u * PLSZ
                             : baseX + (long)(u - CA) * PLSZ;
    };

    float acc[COBLK][4];
#pragma unroll
    for (int o = 0; o < COBLK; ++o) {
        float b_ = bias[bnOff + o0 + o];
#pragma unroll
        for (int j = 0; j < 4; ++j) acc[o][j] = b_;
    }

#pragma unroll 1
    for (int c = 0; c < CIN; ++c) {
        const float* __restrict__ ip = chp(c);
        float tap[3][6];
#pragma unroll
        for (int r = 0; r < 3; ++r) {
            f4 q  = *(const uf4*)(ip + r * PROW);
            f2 q2 = *(const uf2*)(ip + r * PROW + 4);
            tap[r][0] = q.x; tap[r][1] = q.y; tap[r][2] = q.z;
            tap[r][3] = q.w; tap[r][4] = q2.x; tap[r][5] = q2.y;
        }
        const float* __restrict__ wi = wb + ((long)c * COTOT + o0) * 9;  // 108 contiguous
#pragma unroll
        for (int o = 0; o < COBLK; ++o)
#pragma unroll
            for (int kr = 0; kr < 3; ++kr)
#pragma unroll
                for (int kc = 0; kc < 3; ++kc) {
                    float w = wi[o * 9 + kr * 3 + kc];
#pragma unroll
                    for (int j = 0; j < 4; ++j)
                        acc[o][j] = fmaf(w, tap[kr][kc + j], acc[o][j]);
                }
    }

    long obase = (long)s * COTOT * PLSZ + (long)o0 * PLSZ + (y + 1) * PROW + 4 * xc + 1;
#pragma unroll
    for (int o = 0; o < COBLK; ++o) {
        f4 r;
        r.x = fmaxf(acc[o][0], 0.f); r.y = fmaxf(acc[o][1], 0.f);
        r.z = fmaxf(acc[o][2], 0.f); r.w = fmaxf(acc[o][3], 0.f);
        *(uf4*)(actOut + obase + (long)o * PLSZ) = r;
    }
}

// ---- final per-sample 1x1 conv (weights [c][11]), fp32 output.
template<int CA, int CX, int CO>
__global__ __launch_bounds__(256, 4)
void conv1x1(const float* __restrict__ actIn, const float* __restrict__ padx,
             const float* __restrict__ wAll, int wOff,
             float* __restrict__ outF, int b0)
{
    constexpr int CIN = CA + CX;
    const int s = blockIdx.y, gb = b0 + s;
    const int p = blockIdx.x * 256 + threadIdx.x;
    const int off = ((p >> 7) + 1) * PROW + (p & 127) + 1;
    const float* __restrict__ wb = wAll + (long)gb * WPER + wOff;
    const float* __restrict__ baseA = actIn + (long)s * CA * PLSZ + off;
    const float* __restrict__ baseX = padx + (long)gb * 10 * PLSZ + off;

    auto chp = [&](int u) -> const float* {
        return (u < CA) ? baseA + (long)u * PLSZ
                        : baseX + (long)(u - CA) * PLSZ;
    };

    float acc[CO];
#pragma unroll
    for (int o = 0; o < CO; ++o) acc[o] = 0.f;

#pragma unroll 1
    for (int c = 0; c < CIN; ++c) {
        float v = *chp(c);
        const float* __restrict__ wc = wb + c * CO;   // 11 contiguous
#pragma unroll
        for (int o = 0; o < CO; ++o) acc[o] = fmaf(wc[o], v, acc[o]);
    }
#pragma unroll
    for (int o = 0; o < CO; ++o)
        outF[((long)gb * CO + o) * HW + p] = acc[o];
}

extern "C" void kernel_launch(void* const* d_in, const int* in_sizes, int n_in,
                              void* d_out, int out_size, void* d_ws, size_t ws_size,
                              hipStream_t stream)
{
    const float *x = (const float*)d_in[0], *w1 = (const float*)d_in[1],
                *w2 = (const float*)d_in[2], *w3 = (const float*)d_in[3],
                *w4 = (const float*)d_in[4], *g  = (const float*)d_in[5],
                *be = (const float*)d_in[6], *mu = (const float*)d_in[7],
                *va = (const float*)d_in[8];
    if (n_in == 9) {   // identify by size signature (fallback: dict order)
        const float* big801[2] = {nullptr, nullptr}; int n801 = 0;
        const float* bn156[4]  = {nullptr, nullptr, nullptr, nullptr}; int n156 = 0;
        const float *fx = nullptr, *fw1 = nullptr, *fw4 = nullptr;
        for (int i = 0; i < 9; ++i) {
            int sz = in_sizes[i];
            if      (sz == 10485760) fx  = (const float*)d_in[i];
            else if (sz ==   235008) fw1 = (const float*)d_in[i];
            else if (sz ==   801792) { if (n801 < 2) big801[n801++] = (const float*)d_in[i]; }
            else if (sz ==    15488) fw4 = (const float*)d_in[i];
            else if (sz ==      156) { if (n156 < 4) bn156[n156++] = (const float*)d_in[i]; }
        }
        if (fx && fw1 && fw4 && n801 == 2 && n156 == 4) {
            x = fx; w1 = fw1; w2 = big801[0]; w3 = big801[1]; w4 = fw4;
            g = bn156[0]; be = bn156[1]; mu = bn156[2]; va = bn156[3];
        }
    }
    float* out = (float*)d_out;

    // ws: [weights 7.42MB][bias 1KB][padx 43.9MB][bufA|bufB (padded planes)]
    const size_t wgtB  = (size_t)NB * WPER * 4;
    const size_t biasB = 1024;
    const size_t padxB = (size_t)NB * 10 * PLSZ * 4;
    const size_t hdr   = wgtB + biasB + padxB;
    const size_t per2  = 2ull * 24 * PLSZ * 4;
    float* wcvt  = (float*)d_ws;
    float* bias  = (float*)((char*)d_ws + wgtB);
    float* padx  = (float*)((char*)d_ws + wgtB + biasB);
    size_t avail = ws_size > hdr ? ws_size - hdr : per2;
    int chunk = (int)(avail / per2);
    if (chunk > NB) chunk = NB;
    if (chunk < 1)  chunk = 1;
    float* bufA = (float*)((char*)d_ws + hdr);
    float* bufB = bufA + (size_t)chunk * 24 * PLSZ;

    prep_w<<<2048, 256, 0, stream>>>(w1, w2, w3, w4, g, be, mu, va, wcvt, bias);
    pad_x<<<NB * 10, 256, 0, stream>>>(x, padx);
    zero_borders<<<chunk * 48, 256, 0, stream>>>(bufA);

    for (int b0 = 0; b0 < NB; b0 += chunk) {
        int nb = (NB - b0 < chunk) ? (NB - b0) : chunk;
        dim3 gA(16, nb, 1);   // CO=12 layers
        dim3 gB(16, nb, 2);   // CO=24 layers (o-halves)
        dim3 g1(64, nb);
        conv3< 0,10,12,12><<<gA,256,0,stream>>>(bufA,  padx, wcvt,     0, bias,   0, bufA, b0);
        conv3<12, 0,12,12><<<gA,256,0,stream>>>(bufA,  padx, wcvt,  1080, bias,  12, bufB, b0);
        conv3<12, 0,12,12><<<gA,256,0,stream>>>(bufB,  padx, wcvt,  2376, bias,  24, bufA, b0);
        conv3<12,10,24,12><<<gB,256,0,stream>>>(bufA,  padx, wcvt,  3672, bias,  36, bufB, b0);
        conv3<24, 0,24,12><<<gB,256,0,stream>>>(bufB,  padx, wcvt,  8424, bias,  60, bufA, b0);
        conv3<24, 0,12,12><<<gA,256,0,stream>>>(bufA,  padx, wcvt, 13608, bias,  84, bufB, b0);
        conv3<12,10,24,12><<<gB,256,0,stream>>>(bufB,  padx, wcvt, 16200, bias,  96, bufA, b0);
        conv3<24, 0,24,12><<<gB,256,0,stream>>>(bufA,  padx, wcvt, 20952, bias, 120, bufB, b0);
        conv3<24, 0,12,12><<<gA,256,0,stream>>>(bufB,  padx, wcvt, 26136, bias, 144, bufA, b0);
        conv1x1<12,10,11><<<g1,256,0,stream>>>(bufA, padx, wcvt, 28728, out, b0);
    }
}